// Round 4
// baseline (164.365 us; speedup 1.0000x reference)
//
#include <hip/hip_runtime.h>
#include <math.h>

#define TB 8      // batch
#define TT 128    // tokens
#define TD 768    // dim
#define TH 768    // hidden
#define LN_EPS 1e-5f

// 4-K-row FMA body: consumes wv[0..3] (weight rows ROW..ROW+3, 4 cols/lane)
// against LDS-broadcast activations st[b][ROW..ROW+3].
#define BODY4(WV, ROW)                                                \
  {                                                                   \
    float4 xq[8];                                                     \
    _Pragma("unroll") for (int b = 0; b < 8; ++b)                     \
        xq[b] = *(const float4*)&st[b][(ROW)];                        \
    _Pragma("unroll") for (int k = 0; k < 4; ++k) {                   \
      _Pragma("unroll") for (int b = 0; b < 8; ++b) {                 \
        const float xv = ((const float*)&xq[b])[k];                   \
        acc[b][0] = fmaf(xv, (WV)[k].x, acc[b][0]);                   \
        acc[b][1] = fmaf(xv, (WV)[k].y, acc[b][1]);                   \
        acc[b][2] = fmaf(xv, (WV)[k].z, acc[b][2]);                   \
        acc[b][3] = fmaf(xv, (WV)[k].w, acc[b][3]);                   \
      }                                                               \
    }                                                                 \
  }

// ---------------------------------------------------------------------------
// Fused LN + FF1 + GELU + FF2 + residual. Block = (token t, 128-col slice).
// 256 threads = 4 waves; half-wave owns a 96-row K-chunk (8-way K split);
// lane owns 4 cols (float4 weight loads). Per-token producer/consumer sync
// via agent-scope atomics; all 768 blocks co-resident (3/CU by construction)
// so the spin cannot deadlock.
// ---------------------------------------------------------------------------
__global__ __launch_bounds__(256, 3) void fused_ff_kernel(
    const float* __restrict__ x,      // [B][T][D]
    const float* __restrict__ gamma,  // [T][D]
    const float* __restrict__ beta,   // [T][D]
    const float* __restrict__ W1,     // [T][D][H]
    const float* __restrict__ b1,     // [T][H]
    const float* __restrict__ W2,     // [T][H][D]
    const float* __restrict__ b2,     // [T][D]
    float* __restrict__ hbuf,         // [T][B][H] workspace
    int* __restrict__ cnt,            // [T] zeroed each call
    float* __restrict__ outp) {       // [B][T][D]
  __shared__ float st[TB][TD];        // 24 KB activations (xn, then h)
  __shared__ float red[4][8][128];    // 16 KB cross-wave partials
  const int tid = threadIdx.x;
  const int w = tid >> 6, lane = tid & 63;
  const int half = lane >> 5, l32 = lane & 31;
  const int t = blockIdx.x / 6, slice = blockIdx.x % 6;
  const int cg = l32 * 4;
  const int c = slice * 128 + cg;
  const int r0 = w * 192 + half * 96;

  // ---- prefetch first 8 W1 rows of this chunk (overlaps LN below) ----
  const float* wp1 = W1 + ((size_t)t * TD + r0) * TH + c;
  float4 pA[4], pB[4];
#pragma unroll
  for (int k = 0; k < 4; ++k) pA[k] = *(const float4*)(wp1 + k * TH);
#pragma unroll
  for (int k = 0; k < 4; ++k) pB[k] = *(const float4*)(wp1 + (4 + k) * TH);

  // ---- fused LN for batch row b = 2w + half ----
  {
    const int b = w * 2 + half;
    const float* xr = x + ((size_t)b * TT + t) * TD;
    float4 v[6];
    float s = 0.f, ss = 0.f;
#pragma unroll
    for (int i = 0; i < 6; ++i) {
      v[i] = *(const float4*)(xr + i * 128 + l32 * 4);
      s += v[i].x + v[i].y + v[i].z + v[i].w;
      ss += v[i].x * v[i].x + v[i].y * v[i].y + v[i].z * v[i].z +
            v[i].w * v[i].w;
    }
#pragma unroll
    for (int off = 16; off; off >>= 1) {  // reduce within the 32-lane half
      s  += __shfl_xor(s, off, 64);
      ss += __shfl_xor(ss, off, 64);
    }
    const float mu   = s * (1.f / TD);
    const float var  = ss * (1.f / TD) - mu * mu;
    const float rstd = rsqrtf(var + LN_EPS);
#pragma unroll
    for (int i = 0; i < 6; ++i) {
      const int d = i * 128 + l32 * 4;
      const float4 g  = *(const float4*)(gamma + (size_t)t * TD + d);
      const float4 be = *(const float4*)(beta  + (size_t)t * TD + d);
      float4 o;
      o.x = (v[i].x - mu) * rstd * g.x + be.x;
      o.y = (v[i].y - mu) * rstd * g.y + be.y;
      o.z = (v[i].z - mu) * rstd * g.z + be.z;
      o.w = (v[i].w - mu) * rstd * g.w + be.w;
      *(float4*)&st[b][d] = o;
    }
  }
  __syncthreads();

  // ---- FF1 K-loop ----
  float acc[8][4];
#pragma unroll
  for (int b = 0; b < 8; ++b)
#pragma unroll
    for (int j = 0; j < 4; ++j) acc[b][j] = 0.f;

  BODY4(pA, r0);
  BODY4(pB, r0 + 4);
  {
    const float* wp = wp1 + 8 * TH;
#pragma unroll 2
    for (int dd = 8; dd < 96; dd += 4) {
      float4 wv[4];
#pragma unroll
      for (int k = 0; k < 4; ++k) wv[k] = *(const float4*)(wp + k * TH);
      wp += 4 * TH;
      BODY4(wv, r0 + dd);
    }
  }

#pragma unroll
  for (int b = 0; b < 8; ++b)
#pragma unroll
    for (int j = 0; j < 4; ++j)
      acc[b][j] += __shfl_xor(acc[b][j], 32, 64);
  if (lane < 32) {
#pragma unroll
    for (int b = 0; b < 8; ++b)
      *(float4*)&red[w][b][cg] =
          make_float4(acc[b][0], acc[b][1], acc[b][2], acc[b][3]);
  }
  __syncthreads();

  {  // FF1 epilogue: bias + GELU, write h slice to hbuf[t][b][cols]
    const int b = tid >> 5;
    const int colq = (tid & 31) * 4;
    const int cc = slice * 128 + colq;
    const float4 bias = *(const float4*)(b1 + (size_t)t * TH + cc);
    float4 o;
    float* po = (float*)&o;
    const float* pb = (const float*)&bias;
#pragma unroll
    for (int k = 0; k < 4; ++k) {
      float vv = red[0][b][colq + k] + red[1][b][colq + k] +
                 red[2][b][colq + k] + red[3][b][colq + k] + pb[k];
      po[k] = 0.5f * vv * (1.f + erff(vv * 0.7071067811865476f));
    }
    *(float4*)(hbuf + ((size_t)t * TB + b) * TH + cc) = o;
  }
  __syncthreads();  // drains hbuf stores (vmcnt(0) before s_barrier)

  if (tid == 0)
    __hip_atomic_fetch_add(cnt + t, 1, __ATOMIC_RELEASE,
                           __HIP_MEMORY_SCOPE_AGENT);

  // ---- prefetch first 8 W2 rows (overlaps the spin + stage below) ----
  const float* wp2 = W2 + ((size_t)t * TH + r0) * TD + c;
#pragma unroll
  for (int k = 0; k < 4; ++k) pA[k] = *(const float4*)(wp2 + k * TD);
#pragma unroll
  for (int k = 0; k < 4; ++k) pB[k] = *(const float4*)(wp2 + (4 + k) * TD);

  if (tid == 0) {
    while (__hip_atomic_load(cnt + t, __ATOMIC_ACQUIRE,
                             __HIP_MEMORY_SCOPE_AGENT) < 6)
      __builtin_amdgcn_s_sleep(2);
  }
  __syncthreads();

  {  // stage h[t] (8x768, contiguous) into LDS
    const float4* src = (const float4*)(hbuf + (size_t)t * TB * TH);
    float4* dst = (float4*)&st[0][0];
#pragma unroll
    for (int i = 0; i < 6; ++i) dst[tid + i * 256] = src[tid + i * 256];
  }
  __syncthreads();

  // ---- FF2 K-loop ----
#pragma unroll
  for (int b = 0; b < 8; ++b)
#pragma unroll
    for (int j = 0; j < 4; ++j) acc[b][j] = 0.f;

  BODY4(pA, r0);
  BODY4(pB, r0 + 4);
  {
    const float* wp = wp2 + 8 * TD;
#pragma unroll 2
    for (int dd = 8; dd < 96; dd += 4) {
      float4 wv[4];
#pragma unroll
      for (int k = 0; k < 4; ++k) wv[k] = *(const float4*)(wp + k * TD);
      wp += 4 * TD;
      BODY4(wv, r0 + dd);
    }
  }

#pragma unroll
  for (int b = 0; b < 8; ++b)
#pragma unroll
    for (int j = 0; j < 4; ++j)
      acc[b][j] += __shfl_xor(acc[b][j], 32, 64);
  if (lane < 32) {
#pragma unroll
    for (int b = 0; b < 8; ++b)
      *(float4*)&red[w][b][cg] =
          make_float4(acc[b][0], acc[b][1], acc[b][2], acc[b][3]);
  }
  __syncthreads();

  {  // FF2 epilogue: bias + residual, coalesced out
    const int b = tid >> 5;
    const int colq = (tid & 31) * 4;
    const int cc = slice * 128 + colq;
    const size_t off = ((size_t)b * TT + t) * TD + cc;
    const float4 bias = *(const float4*)(b2 + (size_t)t * TD + cc);
    const float4 xres = *(const float4*)(x + off);
    float4 o;
    float* po = (float*)&o;
    const float* pb = (const float*)&bias;
    const float* px = (const float*)&xres;
#pragma unroll
    for (int k = 0; k < 4; ++k)
      po[k] = red[0][b][colq + k] + red[1][b][colq + k] +
              red[2][b][colq + k] + red[3][b][colq + k] + pb[k] + px[k];
    *(float4*)(outp + off) = o;
  }
}

extern "C" void kernel_launch(void* const* d_in, const int* in_sizes, int n_in,
                              void* d_out, int out_size, void* d_ws, size_t ws_size,
                              hipStream_t stream) {
  const float* x     = (const float*)d_in[0];
  const float* gamma = (const float*)d_in[1];
  const float* beta  = (const float*)d_in[2];
  const float* W1    = (const float*)d_in[3];
  const float* b1    = (const float*)d_in[4];
  const float* W2    = (const float*)d_in[5];
  const float* b2    = (const float*)d_in[6];
  float* out = (float*)d_out;

  float* hbuf = (float*)d_ws;  // [T][B][H] = 3 MB
  int* cnt = (int*)((char*)d_ws + (size_t)TT * TB * TH * sizeof(float));

  hipMemsetAsync(cnt, 0, TT * sizeof(int), stream);
  fused_ff_kernel<<<TT * 6, 256, 0, stream>>>(x, gamma, beta, W1, b1, W2, b2,
                                              hbuf, cnt, out);
}

// Round 5
// 120.020 us; speedup vs baseline: 1.3695x; 1.3695x over previous
//
#include <hip/hip_runtime.h>
#include <math.h>

#define TB 8      // batch
#define TT 128    // tokens
#define TD 768    // dim
#define TH 768    // hidden
#define LN_EPS 1e-5f

// 4-K-row FMA body: weight rows in WV[0..3] (4 cols/lane) against
// LDS-broadcast activations st[b][ROW..ROW+3].
#define BODY4(WV, ROW)                                                \
  {                                                                   \
    float4 xq[8];                                                     \
    _Pragma("unroll") for (int b = 0; b < 8; ++b)                     \
        xq[b] = *(const float4*)&st[b][(ROW)];                        \
    _Pragma("unroll") for (int k = 0; k < 4; ++k) {                   \
      _Pragma("unroll") for (int b = 0; b < 8; ++b) {                 \
        const float xv = ((const float*)&xq[b])[k];                   \
        acc[b][0] = fmaf(xv, (WV)[k].x, acc[b][0]);                   \
        acc[b][1] = fmaf(xv, (WV)[k].y, acc[b][1]);                   \
        acc[b][2] = fmaf(xv, (WV)[k].z, acc[b][2]);                   \
        acc[b][3] = fmaf(xv, (WV)[k].w, acc[b][3]);                   \
      }                                                               \
    }                                                                 \
  }

// XCD-chunked block swizzle: hw sends blockIdx%8 -> XCD. Map so XCD x owns
// tokens [16x,16x+16): all 6 slices of a token run concurrently on ONE XCD
// (their 512B fragments of each 3KB weight row merge in time; FF2 hits the
// L2 hbuf lines FF1 wrote). 768 = 8*96, exact bijection.
#define SWIZZLE_TS()                                  \
  const int xcd = blockIdx.x & 7;                     \
  const int j = blockIdx.x >> 3;                      \
  const int t = xcd * 16 + j / 6;                     \
  const int slice = j % 6;

// ---------------------------------------------------------------------------
// FF1 with fused LayerNorm. Block = (token t, 128-col slice of H), 256 thr.
// Half-wave owns a 96-row K-chunk (8-way K split); lane owns 4 cols.
// ---------------------------------------------------------------------------
__global__ __launch_bounds__(256) void ff1_kernel(
    const float* __restrict__ x,      // [B][T][D]
    const float* __restrict__ gamma,  // [T][D]
    const float* __restrict__ beta,   // [T][D]
    const float* __restrict__ W1,     // [T][D][H]
    const float* __restrict__ b1,     // [T][H]
    float* __restrict__ hbuf) {       // [T][B][H]
  __shared__ float st[TB][TD];        // 24 KB normalized activations
  __shared__ float red[4][8][128];    // 16 KB partial sums
  const int tid = threadIdx.x;
  const int w = tid >> 6, lane = tid & 63;
  const int half = lane >> 5, l32 = lane & 31;
  SWIZZLE_TS();
  const int cg = l32 * 4;
  const int c = slice * 128 + cg;
  const int r0 = w * 192 + half * 96;

  // prefetch first 8 W1 rows of this chunk (overlaps LN)
  const float* wp1 = W1 + ((size_t)t * TD + r0) * TH + c;
  float4 pA[4], pB[4];
#pragma unroll
  for (int k = 0; k < 4; ++k) pA[k] = *(const float4*)(wp1 + k * TH);
#pragma unroll
  for (int k = 0; k < 4; ++k) pB[k] = *(const float4*)(wp1 + (4 + k) * TH);

  {  // ---- fused LN for batch row b = 2w + half
    const int b = w * 2 + half;
    const float* xr = x + ((size_t)b * TT + t) * TD;
    float4 v[6];
    float s = 0.f, ss = 0.f;
#pragma unroll
    for (int i = 0; i < 6; ++i) {
      v[i] = *(const float4*)(xr + i * 128 + l32 * 4);
      s += v[i].x + v[i].y + v[i].z + v[i].w;
      ss += v[i].x * v[i].x + v[i].y * v[i].y + v[i].z * v[i].z +
            v[i].w * v[i].w;
    }
#pragma unroll
    for (int off = 16; off; off >>= 1) {  // reduce within the 32-lane half
      s  += __shfl_xor(s, off, 64);
      ss += __shfl_xor(ss, off, 64);
    }
    const float mu   = s * (1.f / TD);
    const float var  = ss * (1.f / TD) - mu * mu;
    const float rstd = rsqrtf(var + LN_EPS);
#pragma unroll
    for (int i = 0; i < 6; ++i) {
      const int d = i * 128 + l32 * 4;
      const float4 g  = *(const float4*)(gamma + (size_t)t * TD + d);
      const float4 be = *(const float4*)(beta  + (size_t)t * TD + d);
      float4 o;
      o.x = (v[i].x - mu) * rstd * g.x + be.x;
      o.y = (v[i].y - mu) * rstd * g.y + be.y;
      o.z = (v[i].z - mu) * rstd * g.z + be.z;
      o.w = (v[i].w - mu) * rstd * g.w + be.w;
      *(float4*)&st[b][d] = o;
    }
  }
  __syncthreads();

  float acc[8][4];
#pragma unroll
  for (int b = 0; b < 8; ++b)
#pragma unroll
    for (int j2 = 0; j2 < 4; ++j2) acc[b][j2] = 0.f;

  BODY4(pA, r0);
  BODY4(pB, r0 + 4);
  {
    const float* wp = wp1 + 8 * TH;
#pragma unroll 2
    for (int dd = 8; dd < 96; dd += 4) {
      float4 wv[4];
#pragma unroll
      for (int k = 0; k < 4; ++k) wv[k] = *(const float4*)(wp + k * TH);
      wp += 4 * TH;
      BODY4(wv, r0 + dd);
    }
  }

#pragma unroll
  for (int b = 0; b < 8; ++b)
#pragma unroll
    for (int j2 = 0; j2 < 4; ++j2)
      acc[b][j2] += __shfl_xor(acc[b][j2], 32, 64);
  if (lane < 32) {
#pragma unroll
    for (int b = 0; b < 8; ++b)
      *(float4*)&red[w][b][cg] =
          make_float4(acc[b][0], acc[b][1], acc[b][2], acc[b][3]);
  }
  __syncthreads();

  {  // epilogue: bias + GELU, thread -> (batch row, 4-col group)
    const int b = tid >> 5;
    const int colq = (tid & 31) * 4;
    const int cc = slice * 128 + colq;
    const float4 bias = *(const float4*)(b1 + (size_t)t * TH + cc);
    float4 o;
    float* po = (float*)&o;
    const float* pb = (const float*)&bias;
#pragma unroll
    for (int k = 0; k < 4; ++k) {
      float vv = red[0][b][colq + k] + red[1][b][colq + k] +
                 red[2][b][colq + k] + red[3][b][colq + k] + pb[k];
      po[k] = 0.5f * vv * (1.f + erff(vv * 0.7071067811865476f));
    }
    *(float4*)(hbuf + ((size_t)t * TB + b) * TH + cc) = o;
  }
}

// ---------------------------------------------------------------------------
// FF2: out = h @ W2 + b2 + x. Same structure; same swizzle so hbuf[t] is
// L2-resident on this XCD.
// ---------------------------------------------------------------------------
__global__ __launch_bounds__(256) void ff2_kernel(
    const float* __restrict__ hbuf, // [T][B][H]
    const float* __restrict__ W2,   // [T][H][D]
    const float* __restrict__ b2,   // [T][D]
    const float* __restrict__ x,    // [B][T][D]
    float* __restrict__ out) {      // [B][T][D]
  __shared__ float st[TB][TH];
  __shared__ float red[4][8][128];
  const int tid = threadIdx.x;
  const int w = tid >> 6, lane = tid & 63;
  const int half = lane >> 5, l32 = lane & 31;
  SWIZZLE_TS();
  const int cg = l32 * 4;
  const int c = slice * 128 + cg;
  const int r0 = w * 192 + half * 96;

  // prefetch first 8 W2 rows (overlaps the hbuf stage)
  const float* wp2 = W2 + ((size_t)t * TH + r0) * TD + c;
  float4 pA[4], pB[4];
#pragma unroll
  for (int k = 0; k < 4; ++k) pA[k] = *(const float4*)(wp2 + k * TD);
#pragma unroll
  for (int k = 0; k < 4; ++k) pB[k] = *(const float4*)(wp2 + (4 + k) * TD);

  {  // contiguous stage: hbuf[t] is [8][768] = exactly st's layout
    const float4* src = (const float4*)(hbuf + (size_t)t * TB * TH);
    float4* dst = (float4*)&st[0][0];
#pragma unroll
    for (int i = 0; i < 6; ++i) dst[tid + i * 256] = src[tid + i * 256];
  }
  __syncthreads();

  float acc[8][4];
#pragma unroll
  for (int b = 0; b < 8; ++b)
#pragma unroll
    for (int j2 = 0; j2 < 4; ++j2) acc[b][j2] = 0.f;

  BODY4(pA, r0);
  BODY4(pB, r0 + 4);
  {
    const float* wp = wp2 + 8 * TD;
#pragma unroll 2
    for (int dd = 8; dd < 96; dd += 4) {
      float4 wv[4];
#pragma unroll
      for (int k = 0; k < 4; ++k) wv[k] = *(const float4*)(wp + k * TD);
      wp += 4 * TD;
      BODY4(wv, r0 + dd);
    }
  }

#pragma unroll
  for (int b = 0; b < 8; ++b)
#pragma unroll
    for (int j2 = 0; j2 < 4; ++j2)
      acc[b][j2] += __shfl_xor(acc[b][j2], 32, 64);
  if (lane < 32) {
#pragma unroll
    for (int b = 0; b < 8; ++b)
      *(float4*)&red[w][b][cg] =
          make_float4(acc[b][0], acc[b][1], acc[b][2], acc[b][3]);
  }
  __syncthreads();

  {  // epilogue: bias + residual, coalesced out
    const int b = tid >> 5;
    const int colq = (tid & 31) * 4;
    const int cc = slice * 128 + colq;
    const size_t off = ((size_t)b * TT + t) * TD + cc;
    const float4 bias = *(const float4*)(b2 + (size_t)t * TD + cc);
    const float4 xres = *(const float4*)(x + off);
    float4 o;
    float* po = (float*)&o;
    const float* pb = (const float*)&bias;
    const float* px = (const float*)&xres;
#pragma unroll
    for (int k = 0; k < 4; ++k)
      po[k] = red[0][b][colq + k] + red[1][b][colq + k] +
              red[2][b][colq + k] + red[3][b][colq + k] + pb[k] + px[k];
    *(float4*)(out + off) = o;
  }
}

extern "C" void kernel_launch(void* const* d_in, const int* in_sizes, int n_in,
                              void* d_out, int out_size, void* d_ws, size_t ws_size,
                              hipStream_t stream) {
  const float* x     = (const float*)d_in[0];
  const float* gamma = (const float*)d_in[1];
  const float* beta  = (const float*)d_in[2];
  const float* W1    = (const float*)d_in[3];
  const float* b1    = (const float*)d_in[4];
  const float* W2    = (const float*)d_in[5];
  const float* b2    = (const float*)d_in[6];
  float* out = (float*)d_out;

  float* hbuf = (float*)d_ws;   // [T][B][H] = 3 MB

  ff1_kernel<<<TT * 6, 256, 0, stream>>>(x, gamma, beta, W1, b1, hbuf);
  ff2_kernel<<<TT * 6, 256, 0, stream>>>(hbuf, W2, b2, x, out);
}